// Round 1
// baseline (1210.961 us; speedup 1.0000x reference)
//
#include <hip/hip_runtime.h>
#include <hip/hip_bf16.h>
#include <cmath>

// Problem constants
#define BATCH   16
#define SEQ     2048
#define IN_DIM  57
#define D_MODEL 64
#define HEADDIM 32
#define D_STATE 32
#define OUT_DIM 6
#define D_INNER 128
#define NHEADS  4
#define D_CONV  4
#define D_XBC   192          // D_INNER + 2*D_STATE
#define D_IN_PROJ 324        // 2*D_INNER + 2*D_STATE + NHEADS
#define BL      (BATCH*SEQ)  // 32768

// Workspace layout (floats)
#define OFF_WF   ((size_t)0)                      // 57*324 = 18468
#define OFF_BF   ((size_t)18496)                  // 324
#define OFF_ZX   ((size_t)18848)                  // BL*324 = 10616832
#define OFF_XBC  (OFF_ZX + (size_t)BL*D_IN_PROJ)  // BL*192
#define OFF_DT   (OFF_XBC + (size_t)BL*D_XBC)     // BL*4
#define OFF_DEC  (OFF_DT + (size_t)BL*NHEADS)     // BL*4
#define OFF_Y    (OFF_DEC + (size_t)BL*NHEADS)    // BL*128
#define OFF_PL   (OFF_Y + (size_t)BL*D_INNER)     // 16*64

// ---------------------------------------------------------------------------
// Kernel 1: W_fused[r][j] = sum_m W_lin[r][m]*W_in[m][j];  b_fused = b_lin@W_in
__global__ void fuse_w_kernel(const float* __restrict__ W_lin,
                              const float* __restrict__ b_lin,
                              const float* __restrict__ W_in,
                              float* __restrict__ Wf, float* __restrict__ bf) {
    int idx = blockIdx.x * 256 + threadIdx.x;
    if (idx >= 58 * D_IN_PROJ) return;
    int r = idx / D_IN_PROJ;
    int j = idx - r * D_IN_PROJ;
    const float* v = (r < IN_DIM) ? (W_lin + r * D_MODEL) : b_lin;
    float acc = 0.f;
#pragma unroll 8
    for (int m = 0; m < D_MODEL; ++m) acc += v[m] * W_in[m * D_IN_PROJ + j];
    if (r < IN_DIM) Wf[r * D_IN_PROJ + j] = acc;
    else            bf[j] = acc;
}

// ---------------------------------------------------------------------------
// Kernel 2: zxbcdt[row][j0..j0+3] = bf + x[row][:] @ Wf[:, j0..j0+3]
// one thread per (row, col-group-of-4); 81 col groups per row
__global__ void inproj_kernel(const float* __restrict__ x,
                              const float* __restrict__ Wf,
                              const float* __restrict__ bf,
                              float* __restrict__ zx) {
    int gid = blockIdx.x * 256 + threadIdx.x;   // grid sized exactly: BL*81 threads
    int row = gid / 81;
    int cg  = gid - row * 81;
    int j0  = cg * 4;
    const float* xr = x + (size_t)row * IN_DIM;
    float4 acc = *(const float4*)(bf + j0);
    const float* w = Wf + j0;
#pragma unroll 3
    for (int k = 0; k < IN_DIM; ++k) {
        float xv = xr[k];
        float4 wv = *(const float4*)(w + (size_t)k * D_IN_PROJ);
        acc.x += xv * wv.x; acc.y += xv * wv.y;
        acc.z += xv * wv.z; acc.w += xv * wv.w;
    }
    *(float4*)(zx + (size_t)row * D_IN_PROJ + j0) = acc;
}

// ---------------------------------------------------------------------------
// Kernel 3: depthwise causal conv(4) + bias + SiLU on channels 128..319 of
// zxbcdt -> xBC; and dt = softplus(zxbcdt[...,320+h] + dt_bias), decay=exp(dt*A)
__global__ void conv_dt_kernel(const float* __restrict__ zx,
                               const float* __restrict__ conv_w,
                               const float* __restrict__ conv_b,
                               const float* __restrict__ dt_bias,
                               const float* __restrict__ A_log,
                               float* __restrict__ xBC,
                               float* __restrict__ dtb,
                               float* __restrict__ dcb) {
    int bl = blockIdx.x;            // 0..BL-1
    int l = bl & (SEQ - 1);
    int tid = threadIdx.x;
    const float* src = zx + (size_t)bl * D_IN_PROJ + D_INNER;
    if (tid < D_XBC) {
        float w0 = conv_w[tid*4+0], w1 = conv_w[tid*4+1];
        float w2 = conv_w[tid*4+2], w3 = conv_w[tid*4+3];
        float acc = conv_b[tid] + src[tid] * w3;
        if (l >= 1) acc += src[tid - 1*D_IN_PROJ] * w2;
        if (l >= 2) acc += src[tid - 2*D_IN_PROJ] * w1;
        if (l >= 3) acc += src[tid - 3*D_IN_PROJ] * w0;
        float s = acc / (1.f + expf(-acc));      // SiLU
        xBC[(size_t)bl * D_XBC + tid] = s;
    } else if (tid < D_XBC + NHEADS) {
        int h = tid - D_XBC;
        float v = zx[(size_t)bl * D_IN_PROJ + 320 + h] + dt_bias[h];
        float dtv = (v > 20.f) ? v : log1pf(expf(v));
        dtb[(size_t)bl * NHEADS + h] = dtv;
        float A = -expf(A_log[h]);
        dcb[(size_t)bl * NHEADS + h] = expf(dtv * A);
    }
}

// ---------------------------------------------------------------------------
// Kernel 4: sequential selective scan. One block per (b,h); 256 threads;
// thread (p = tid>>3, n-chunk = (tid&7)*4) holds 4 state elems in a float4.
__global__ __launch_bounds__(256) void scan_kernel(
        const float* __restrict__ xBC, const float* __restrict__ dtb,
        const float* __restrict__ dcb, const float* __restrict__ Dp,
        float* __restrict__ yraw) {
    int b = blockIdx.x >> 2, h = blockIdx.x & 3;
    int tid = threadIdx.x;
    int p  = tid >> 3;
    int nb = (tid & 7) * 4;
    float Dh = Dp[h];
    float4 s = make_float4(0.f, 0.f, 0.f, 0.f);
    const float* xc  = xBC + (size_t)b * SEQ * D_XBC;
    const float* dtp = dtb + (size_t)b * SEQ * NHEADS + h;
    const float* dcp = dcb + (size_t)b * SEQ * NHEADS + h;
    float* yp = yraw + (size_t)b * SEQ * D_INNER + h * HEADDIM + p;
#pragma unroll 2
    for (int l = 0; l < SEQ; ++l) {
        float dtv = dtp[l * NHEADS];
        float dec = dcp[l * NHEADS];
        const float* rowp = xc + (size_t)l * D_XBC;
        float xv = rowp[h * HEADDIM + p];
        float4 Bv = *(const float4*)(rowp + D_INNER + nb);
        float4 Cv = *(const float4*)(rowp + D_INNER + D_STATE + nb);
        float coef = dtv * xv;
        s.x = s.x * dec + coef * Bv.x;
        s.y = s.y * dec + coef * Bv.y;
        s.z = s.z * dec + coef * Bv.z;
        s.w = s.w * dec + coef * Bv.w;
        float part = s.x*Cv.x + s.y*Cv.y + s.z*Cv.z + s.w*Cv.w;
        part += __shfl_xor(part, 1);
        part += __shfl_xor(part, 2);
        part += __shfl_xor(part, 4);
        if ((tid & 7) == 0) yp[(size_t)l * D_INNER] = part + Dh * xv;
    }
}

// ---------------------------------------------------------------------------
// Kernel 5: gate*silu(z), RMSNorm, @W_out, partial mean-pool (atomicAdd).
// One block per (b, chunk of 128 l); 256 threads.
__global__ __launch_bounds__(256) void gate_out_kernel(
        const float* __restrict__ yraw, const float* __restrict__ zx,
        const float* __restrict__ norm_w, const float* __restrict__ W_out,
        float* __restrict__ pooled) {
    int b = blockIdx.x >> 4;
    int l0 = (blockIdx.x & 15) * 128;
    int tid = threadIdx.x;
    __shared__ float gn[D_INNER];
    __shared__ float red[4];
    int j = tid >> 2, seg = tid & 3;
    float acc = 0.f;
    for (int li = 0; li < 128; ++li) {
        int bl = b * SEQ + l0 + li;
        float gi = 0.f, sq = 0.f;
        if (tid < D_INNER) {
            float yv = yraw[(size_t)bl * D_INNER + tid];
            float zv = zx[(size_t)bl * D_IN_PROJ + tid];
            gi = yv * (zv / (1.f + expf(-zv)));
            sq = gi * gi;
        }
#pragma unroll
        for (int m = 1; m < 64; m <<= 1) sq += __shfl_xor(sq, m);
        if ((tid & 63) == 0) red[tid >> 6] = sq;
        __syncthreads();
        float tot = red[0] + red[1] + red[2] + red[3];
        float rms = 1.0f / sqrtf(tot * (1.f / 128.f) + 1e-5f);
        if (tid < D_INNER) gn[tid] = gi * rms * norm_w[tid];
        __syncthreads();
        // matvec: out64[j] = sum_i gn[i]*W_out[i][j]
        float pval = 0.f;
        const float* wo = W_out + (size_t)(seg * 32) * D_MODEL + j;
#pragma unroll 8
        for (int k = 0; k < 32; ++k) pval += gn[seg * 32 + k] * wo[(size_t)k * D_MODEL];
        pval += __shfl_xor(pval, 1);
        pval += __shfl_xor(pval, 2);
        if (seg == 0) acc += pval;
        __syncthreads();   // protect gn/red before next iteration
    }
    if (seg == 0) atomicAdd(&pooled[b * D_MODEL + j], acc);
}

// ---------------------------------------------------------------------------
// Kernel 6: out[b][o] = b_cls[o] + (pooled[b]/SEQ) @ W_cls[:,o]
__global__ void head_kernel(const float* __restrict__ pooled,
                            const float* __restrict__ W_cls,
                            const float* __restrict__ b_cls,
                            float* __restrict__ out) {
    int tid = threadIdx.x;
    if (tid >= BATCH * OUT_DIM) return;
    int b = tid / OUT_DIM, o = tid - b * OUT_DIM;
    float acc = 0.f;
#pragma unroll 8
    for (int jj = 0; jj < D_MODEL; ++jj)
        acc += pooled[b * D_MODEL + jj] * W_cls[jj * OUT_DIM + o];
    out[b * OUT_DIM + o] = acc * (1.f / (float)SEQ) + b_cls[o];
}

// ---------------------------------------------------------------------------
extern "C" void kernel_launch(void* const* d_in, const int* in_sizes, int n_in,
                              void* d_out, int out_size, void* d_ws, size_t ws_size,
                              hipStream_t stream) {
    const float* x       = (const float*)d_in[0];
    const float* W_lin   = (const float*)d_in[1];
    const float* b_lin   = (const float*)d_in[2];
    const float* W_in    = (const float*)d_in[3];
    const float* conv_w  = (const float*)d_in[4];
    const float* conv_b  = (const float*)d_in[5];
    const float* dt_bias = (const float*)d_in[6];
    const float* A_log   = (const float*)d_in[7];
    const float* Dp      = (const float*)d_in[8];
    const float* norm_w  = (const float*)d_in[9];
    const float* W_out   = (const float*)d_in[10];
    const float* W_cls   = (const float*)d_in[11];
    const float* b_cls   = (const float*)d_in[12];
    float* out = (float*)d_out;

    float* ws = (float*)d_ws;
    float* Wf   = ws + OFF_WF;
    float* bf   = ws + OFF_BF;
    float* zx   = ws + OFF_ZX;
    float* xBC  = ws + OFF_XBC;
    float* dtb  = ws + OFF_DT;
    float* dcb  = ws + OFF_DEC;
    float* yraw = ws + OFF_Y;
    float* pooled = ws + OFF_PL;

    // zero the pooled accumulator (ws is poisoned before every call)
    hipMemsetAsync(pooled, 0, BATCH * D_MODEL * sizeof(float), stream);

    // 1) fused weight precompute: 58*324 = 18792 threads
    fuse_w_kernel<<<(58 * D_IN_PROJ + 255) / 256, 256, 0, stream>>>(W_lin, b_lin, W_in, Wf, bf);

    // 2) in-projection: BL*81 threads (exactly 10368 blocks of 256)
    inproj_kernel<<<(BL * 81) / 256, 256, 0, stream>>>(x, Wf, bf, zx);

    // 3) conv + dt/decay: one block per (b,l)
    conv_dt_kernel<<<BL, 256, 0, stream>>>(zx, conv_w, conv_b, dt_bias, A_log, xBC, dtb, dcb);

    // 4) sequential scan: one block per (b,h)
    scan_kernel<<<BATCH * NHEADS, 256, 0, stream>>>(xBC, dtb, dcb, Dp, yraw);

    // 5) gate + RMSNorm + out-proj + pooling: 16 b * 16 chunks
    gate_out_kernel<<<BATCH * 16, 256, 0, stream>>>(yraw, zx, norm_w, W_out, pooled);

    // 6) classifier head
    head_kernel<<<1, 128, 0, stream>>>(pooled, W_cls, b_cls, out);
}

// Round 2
// 507.867 us; speedup vs baseline: 2.3844x; 2.3844x over previous
//
#include <hip/hip_runtime.h>
#include <hip/hip_bf16.h>
#include <cmath>

// Problem constants
#define BATCH   16
#define SEQ     2048
#define IN_DIM  57
#define D_MODEL 64
#define HEADDIM 32
#define D_STATE 32
#define OUT_DIM 6
#define D_INNER 128
#define NHEADS  4
#define D_CONV  4
#define D_XBC   192          // D_INNER + 2*D_STATE
#define D_IN_PROJ 324        // 2*D_INNER + 2*D_STATE + NHEADS
#define BL      (BATCH*SEQ)  // 32768

// Chunked scan config
#define NCHUNK  32
#define CLEN    (SEQ / NCHUNK)   // 64

// Workspace layout (floats)
#define OFF_WF   ((size_t)0)                      // 57*324 = 18468
#define OFF_BF   ((size_t)18496)                  // 324
#define OFF_ZX   ((size_t)18848)                  // BL*324
#define OFF_XBC  (OFF_ZX + (size_t)BL*D_IN_PROJ)  // BL*192
#define OFF_DT   (OFF_XBC + (size_t)BL*D_XBC)     // BL*4
#define OFF_DEC  (OFF_DT + (size_t)BL*NHEADS)     // BL*4
#define OFF_Y    (OFF_DEC + (size_t)BL*NHEADS)    // BL*128
#define OFF_PL   (OFF_Y + (size_t)BL*D_INNER)     // 16*64 -> 1024
#define OFF_SB   (OFF_PL + (size_t)1024)          // 64*32*1024 chunk states
#define OFF_P    (OFF_SB + (size_t)64*NCHUNK*1024)// 64*32 decay products
// total ~ 23.5M floats ~ 94 MB

// ---------------------------------------------------------------------------
// Kernel 1: W_fused[r][j] = sum_m W_lin[r][m]*W_in[m][j];  b_fused = b_lin@W_in
__global__ void fuse_w_kernel(const float* __restrict__ W_lin,
                              const float* __restrict__ b_lin,
                              const float* __restrict__ W_in,
                              float* __restrict__ Wf, float* __restrict__ bf) {
    int idx = blockIdx.x * 256 + threadIdx.x;
    if (idx >= 58 * D_IN_PROJ) return;
    int r = idx / D_IN_PROJ;
    int j = idx - r * D_IN_PROJ;
    const float* v = (r < IN_DIM) ? (W_lin + r * D_MODEL) : b_lin;
    float acc = 0.f;
#pragma unroll 8
    for (int m = 0; m < D_MODEL; ++m) acc += v[m] * W_in[m * D_IN_PROJ + j];
    if (r < IN_DIM) Wf[r * D_IN_PROJ + j] = acc;
    else            bf[j] = acc;
}

// ---------------------------------------------------------------------------
// Kernel 2: zxbcdt[row][j0..j0+3] = bf + x[row][:] @ Wf[:, j0..j0+3]
__global__ void inproj_kernel(const float* __restrict__ x,
                              const float* __restrict__ Wf,
                              const float* __restrict__ bf,
                              float* __restrict__ zx) {
    int gid = blockIdx.x * 256 + threadIdx.x;
    int row = gid / 81;
    int cg  = gid - row * 81;
    int j0  = cg * 4;
    const float* xr = x + (size_t)row * IN_DIM;
    float4 acc = *(const float4*)(bf + j0);
    const float* w = Wf + j0;
#pragma unroll 3
    for (int k = 0; k < IN_DIM; ++k) {
        float xv = xr[k];
        float4 wv = *(const float4*)(w + (size_t)k * D_IN_PROJ);
        acc.x += xv * wv.x; acc.y += xv * wv.y;
        acc.z += xv * wv.z; acc.w += xv * wv.w;
    }
    *(float4*)(zx + (size_t)row * D_IN_PROJ + j0) = acc;
}

// ---------------------------------------------------------------------------
// Kernel 3: depthwise causal conv(4) + bias + SiLU; dt softplus; decay exp(dt*A)
__global__ void conv_dt_kernel(const float* __restrict__ zx,
                               const float* __restrict__ conv_w,
                               const float* __restrict__ conv_b,
                               const float* __restrict__ dt_bias,
                               const float* __restrict__ A_log,
                               float* __restrict__ xBC,
                               float* __restrict__ dtb,
                               float* __restrict__ dcb) {
    int bl = blockIdx.x;
    int l = bl & (SEQ - 1);
    int tid = threadIdx.x;
    const float* src = zx + (size_t)bl * D_IN_PROJ + D_INNER;
    if (tid < D_XBC) {
        float w0 = conv_w[tid*4+0], w1 = conv_w[tid*4+1];
        float w2 = conv_w[tid*4+2], w3 = conv_w[tid*4+3];
        float acc = conv_b[tid] + src[tid] * w3;
        if (l >= 1) acc += src[tid - 1*D_IN_PROJ] * w2;
        if (l >= 2) acc += src[tid - 2*D_IN_PROJ] * w1;
        if (l >= 3) acc += src[tid - 3*D_IN_PROJ] * w0;
        float s = acc / (1.f + expf(-acc));      // SiLU
        xBC[(size_t)bl * D_XBC + tid] = s;
    } else if (tid < D_XBC + NHEADS) {
        int h = tid - D_XBC;
        float v = zx[(size_t)bl * D_IN_PROJ + 320 + h] + dt_bias[h];
        float dtv = (v > 20.f) ? v : log1pf(expf(v));
        dtb[(size_t)bl * NHEADS + h] = dtv;
        float A = -expf(A_log[h]);
        dcb[(size_t)bl * NHEADS + h] = expf(dtv * A);
    }
}

// ---------------------------------------------------------------------------
// Chunked scan, phase 1: per (b,h,chunk) run the recurrence with s0=0;
// emit final chunk state (32x32) and scalar decay product P of the chunk.
// thread layout: p = tid>>3 (0..31), nb = (tid&7)*4.
__global__ __launch_bounds__(256) void scan_phase1_kernel(
        const float* __restrict__ xBC, const float* __restrict__ dtb,
        const float* __restrict__ dcb,
        float* __restrict__ sbuf, float* __restrict__ Pbuf) {
    int c  = blockIdx.x & (NCHUNK - 1);
    int bh = blockIdx.x >> 5;
    int b = bh >> 2, h = bh & 3;
    int tid = threadIdx.x;
    int p  = tid >> 3;
    int nb = (tid & 7) * 4;
    float4 s = make_float4(0.f, 0.f, 0.f, 0.f);
    float pacc = 1.f;
    const float* xc  = xBC + (size_t)b * SEQ * D_XBC;
    const float* dtp = dtb + (size_t)b * SEQ * NHEADS + h;
    const float* dcp = dcb + (size_t)b * SEQ * NHEADS + h;
    int l0 = c * CLEN;
#pragma unroll 4
    for (int i = 0; i < CLEN; ++i) {
        int l = l0 + i;
        float dtv = dtp[l * NHEADS];
        float dec = dcp[l * NHEADS];
        const float* rowp = xc + (size_t)l * D_XBC;
        float xv = rowp[h * HEADDIM + p];
        float4 Bv = *(const float4*)(rowp + D_INNER + nb);
        float coef = dtv * xv;
        s.x = s.x * dec + coef * Bv.x;
        s.y = s.y * dec + coef * Bv.y;
        s.z = s.z * dec + coef * Bv.z;
        s.w = s.w * dec + coef * Bv.w;
        pacc *= dec;
    }
    ((float4*)sbuf)[(size_t)(bh * NCHUNK + c) * 256 + tid] = s;
    if (tid == 0) Pbuf[bh * NCHUNK + c] = pacc;
}

// ---------------------------------------------------------------------------
// Phase 2: per (b,h) sequentially combine chunk states; overwrite sbuf[c]
// with the INITIAL state for chunk c.
__global__ __launch_bounds__(256) void scan_phase2_kernel(
        float* __restrict__ sbuf, const float* __restrict__ Pbuf) {
    int bh = blockIdx.x;
    int tid = threadIdx.x;
    float4 run = make_float4(0.f, 0.f, 0.f, 0.f);
    float4* sb = (float4*)sbuf + (size_t)bh * NCHUNK * 256 + tid;
    for (int c = 0; c < NCHUNK; ++c) {
        float4 tmp = sb[(size_t)c * 256];
        float Pv = Pbuf[bh * NCHUNK + c];
        sb[(size_t)c * 256] = run;
        run.x = run.x * Pv + tmp.x;
        run.y = run.y * Pv + tmp.y;
        run.z = run.z * Pv + tmp.z;
        run.w = run.w * Pv + tmp.w;
    }
}

// ---------------------------------------------------------------------------
// Phase 3: per (b,h,chunk) re-run the recurrence seeded with the correct
// initial state, producing y.
__global__ __launch_bounds__(256) void scan_phase3_kernel(
        const float* __restrict__ xBC, const float* __restrict__ dtb,
        const float* __restrict__ dcb, const float* __restrict__ Dp,
        const float* __restrict__ sbuf, float* __restrict__ yraw) {
    int c  = blockIdx.x & (NCHUNK - 1);
    int bh = blockIdx.x >> 5;
    int b = bh >> 2, h = bh & 3;
    int tid = threadIdx.x;
    int p  = tid >> 3;
    int nb = (tid & 7) * 4;
    float Dh = Dp[h];
    float4 s = ((const float4*)sbuf)[(size_t)(bh * NCHUNK + c) * 256 + tid];
    const float* xc  = xBC + (size_t)b * SEQ * D_XBC;
    const float* dtp = dtb + (size_t)b * SEQ * NHEADS + h;
    const float* dcp = dcb + (size_t)b * SEQ * NHEADS + h;
    float* yp = yraw + (size_t)b * SEQ * D_INNER + h * HEADDIM + p;
    int l0 = c * CLEN;
#pragma unroll 2
    for (int i = 0; i < CLEN; ++i) {
        int l = l0 + i;
        float dtv = dtp[l * NHEADS];
        float dec = dcp[l * NHEADS];
        const float* rowp = xc + (size_t)l * D_XBC;
        float xv = rowp[h * HEADDIM + p];
        float4 Bv = *(const float4*)(rowp + D_INNER + nb);
        float4 Cv = *(const float4*)(rowp + D_INNER + D_STATE + nb);
        float coef = dtv * xv;
        s.x = s.x * dec + coef * Bv.x;
        s.y = s.y * dec + coef * Bv.y;
        s.z = s.z * dec + coef * Bv.z;
        s.w = s.w * dec + coef * Bv.w;
        float part = s.x*Cv.x + s.y*Cv.y + s.z*Cv.z + s.w*Cv.w;
        part += __shfl_xor(part, 1);
        part += __shfl_xor(part, 2);
        part += __shfl_xor(part, 4);
        if ((tid & 7) == 0) yp[(size_t)l * D_INNER] = part + Dh * xv;
    }
}

// ---------------------------------------------------------------------------
// Kernel 5: gate*silu(z), RMSNorm, @W_out, partial mean-pool (atomicAdd).
__global__ __launch_bounds__(256) void gate_out_kernel(
        const float* __restrict__ yraw, const float* __restrict__ zx,
        const float* __restrict__ norm_w, const float* __restrict__ W_out,
        float* __restrict__ pooled) {
    int b = blockIdx.x >> 4;
    int l0 = (blockIdx.x & 15) * 128;
    int tid = threadIdx.x;
    __shared__ float gn[D_INNER];
    __shared__ float red[4];
    int j = tid >> 2, seg = tid & 3;
    float acc = 0.f;
    for (int li = 0; li < 128; ++li) {
        int bl = b * SEQ + l0 + li;
        float gi = 0.f, sq = 0.f;
        if (tid < D_INNER) {
            float yv = yraw[(size_t)bl * D_INNER + tid];
            float zv = zx[(size_t)bl * D_IN_PROJ + tid];
            gi = yv * (zv / (1.f + expf(-zv)));
            sq = gi * gi;
        }
#pragma unroll
        for (int m = 1; m < 64; m <<= 1) sq += __shfl_xor(sq, m);
        if ((tid & 63) == 0) red[tid >> 6] = sq;
        __syncthreads();
        float tot = red[0] + red[1] + red[2] + red[3];
        float rms = 1.0f / sqrtf(tot * (1.f / 128.f) + 1e-5f);
        if (tid < D_INNER) gn[tid] = gi * rms * norm_w[tid];
        __syncthreads();
        float pval = 0.f;
        const float* wo = W_out + (size_t)(seg * 32) * D_MODEL + j;
#pragma unroll 8
        for (int k = 0; k < 32; ++k) pval += gn[seg * 32 + k] * wo[(size_t)k * D_MODEL];
        pval += __shfl_xor(pval, 1);
        pval += __shfl_xor(pval, 2);
        if (seg == 0) acc += pval;
        __syncthreads();
    }
    if (seg == 0) atomicAdd(&pooled[b * D_MODEL + j], acc);
}

// ---------------------------------------------------------------------------
// Kernel 6: out[b][o] = b_cls[o] + (pooled[b]/SEQ) @ W_cls[:,o]
__global__ void head_kernel(const float* __restrict__ pooled,
                            const float* __restrict__ W_cls,
                            const float* __restrict__ b_cls,
                            float* __restrict__ out) {
    int tid = threadIdx.x;
    if (tid >= BATCH * OUT_DIM) return;
    int b = tid / OUT_DIM, o = tid - b * OUT_DIM;
    float acc = 0.f;
#pragma unroll 8
    for (int jj = 0; jj < D_MODEL; ++jj)
        acc += pooled[b * D_MODEL + jj] * W_cls[jj * OUT_DIM + o];
    out[b * OUT_DIM + o] = acc * (1.f / (float)SEQ) + b_cls[o];
}

// ---------------------------------------------------------------------------
extern "C" void kernel_launch(void* const* d_in, const int* in_sizes, int n_in,
                              void* d_out, int out_size, void* d_ws, size_t ws_size,
                              hipStream_t stream) {
    const float* x       = (const float*)d_in[0];
    const float* W_lin   = (const float*)d_in[1];
    const float* b_lin   = (const float*)d_in[2];
    const float* W_in    = (const float*)d_in[3];
    const float* conv_w  = (const float*)d_in[4];
    const float* conv_b  = (const float*)d_in[5];
    const float* dt_bias = (const float*)d_in[6];
    const float* A_log   = (const float*)d_in[7];
    const float* Dp      = (const float*)d_in[8];
    const float* norm_w  = (const float*)d_in[9];
    const float* W_out   = (const float*)d_in[10];
    const float* W_cls   = (const float*)d_in[11];
    const float* b_cls   = (const float*)d_in[12];
    float* out = (float*)d_out;

    float* ws = (float*)d_ws;
    float* Wf     = ws + OFF_WF;
    float* bf     = ws + OFF_BF;
    float* zx     = ws + OFF_ZX;
    float* xBC    = ws + OFF_XBC;
    float* dtb    = ws + OFF_DT;
    float* dcb    = ws + OFF_DEC;
    float* yraw   = ws + OFF_Y;
    float* pooled = ws + OFF_PL;
    float* sbuf   = ws + OFF_SB;
    float* Pbuf   = ws + OFF_P;

    hipMemsetAsync(pooled, 0, BATCH * D_MODEL * sizeof(float), stream);

    fuse_w_kernel<<<(58 * D_IN_PROJ + 255) / 256, 256, 0, stream>>>(W_lin, b_lin, W_in, Wf, bf);

    inproj_kernel<<<(BL * 81) / 256, 256, 0, stream>>>(x, Wf, bf, zx);

    conv_dt_kernel<<<BL, 256, 0, stream>>>(zx, conv_w, conv_b, dt_bias, A_log, xBC, dtb, dcb);

    // chunked selective scan
    scan_phase1_kernel<<<BATCH * NHEADS * NCHUNK, 256, 0, stream>>>(xBC, dtb, dcb, sbuf, Pbuf);
    scan_phase2_kernel<<<BATCH * NHEADS, 256, 0, stream>>>(sbuf, Pbuf);
    scan_phase3_kernel<<<BATCH * NHEADS * NCHUNK, 256, 0, stream>>>(xBC, dtb, dcb, Dp, sbuf, yraw);

    gate_out_kernel<<<BATCH * 16, 256, 0, stream>>>(yraw, zx, norm_w, W_out, pooled);

    head_kernel<<<1, 128, 0, stream>>>(pooled, W_cls, b_cls, out);
}

// Round 4
// 297.305 us; speedup vs baseline: 4.0731x; 1.7082x over previous
//
#include <hip/hip_runtime.h>
#include <hip/hip_bf16.h>
#include <cmath>

// Problem constants
#define BATCH   16
#define SEQ     2048
#define IN_DIM  57
#define D_MODEL 64
#define HEADDIM 32
#define D_STATE 32
#define OUT_DIM 6
#define D_INNER 128
#define NHEADS  4
#define D_CONV  4
#define D_XBC   192          // D_INNER + 2*D_STATE
#define D_IN_PROJ 324        // 2*D_INNER + 2*D_STATE + NHEADS
#define BL      (BATCH*SEQ)  // 32768

// Chunked scan config
#define NCHUNK  32
#define CLEN    (SEQ / NCHUNK)   // 64

// Workspace layout (floats)
#define OFF_WF   ((size_t)0)                       // 57*324
#define OFF_BF   ((size_t)18496)                   // 324
#define OFF_ZX   ((size_t)18848)                   // BL*324
#define OFF_XBC  (OFF_ZX  + (size_t)BL*D_IN_PROJ)  // BL*192
#define OFF_DT   (OFF_XBC + (size_t)BL*D_XBC)      // BL*4
#define OFF_DEC  (OFF_DT  + (size_t)BL*NHEADS)     // BL*4
#define OFF_Y    (OFF_DEC + (size_t)BL*NHEADS)     // BL*128
#define OFF_G    (OFF_Y   + (size_t)BL*D_INNER)    // 16*128 = 2048
#define OFF_WOC  (OFF_G   + (size_t)2048)          // 128*6 = 768 (pad 896)
#define OFF_SB   (OFF_WOC + (size_t)896)           // 64*32*1024 chunk states
#define OFF_P    (OFF_SB  + (size_t)64*NCHUNK*1024)// 64*32 decay products
// total ~ 23.5M floats ~ 94 MB

// ---------------------------------------------------------------------------
// Kernel 1: Wf = W_lin@W_in ; bf = b_lin@W_in ; W_oc = W_out@W_cls
__global__ void fuse_w_kernel(const float* __restrict__ W_lin,
                              const float* __restrict__ b_lin,
                              const float* __restrict__ W_in,
                              const float* __restrict__ W_out,
                              const float* __restrict__ W_cls,
                              float* __restrict__ Wf, float* __restrict__ bf,
                              float* __restrict__ Woc) {
    int idx = blockIdx.x * 256 + threadIdx.x;
    if (idx < 58 * D_IN_PROJ) {
        int r = idx / D_IN_PROJ;
        int j = idx - r * D_IN_PROJ;
        const float* v = (r < IN_DIM) ? (W_lin + r * D_MODEL) : b_lin;
        float acc = 0.f;
#pragma unroll 8
        for (int m = 0; m < D_MODEL; ++m) acc += v[m] * W_in[m * D_IN_PROJ + j];
        if (r < IN_DIM) Wf[r * D_IN_PROJ + j] = acc;
        else            bf[j] = acc;
    } else if (idx < 58 * D_IN_PROJ + D_INNER * OUT_DIM) {
        int idx2 = idx - 58 * D_IN_PROJ;
        int i = idx2 / OUT_DIM;
        int o = idx2 - i * OUT_DIM;
        float acc = 0.f;
#pragma unroll 8
        for (int j = 0; j < D_MODEL; ++j)
            acc += W_out[i * D_MODEL + j] * W_cls[j * OUT_DIM + o];
        Woc[i * OUT_DIM + o] = acc;
    }
}

// ---------------------------------------------------------------------------
// Kernel 2: zxbcdt[row][j0..j0+3] = bf + x[row][:] @ Wf[:, j0..j0+3]
__global__ void inproj_kernel(const float* __restrict__ x,
                              const float* __restrict__ Wf,
                              const float* __restrict__ bf,
                              float* __restrict__ zx) {
    int gid = blockIdx.x * 256 + threadIdx.x;
    int row = gid / 81;
    int cg  = gid - row * 81;
    int j0  = cg * 4;
    const float* xr = x + (size_t)row * IN_DIM;
    float4 acc = *(const float4*)(bf + j0);
    const float* w = Wf + j0;
#pragma unroll 3
    for (int k = 0; k < IN_DIM; ++k) {
        float xv = xr[k];
        float4 wv = *(const float4*)(w + (size_t)k * D_IN_PROJ);
        acc.x += xv * wv.x; acc.y += xv * wv.y;
        acc.z += xv * wv.z; acc.w += xv * wv.w;
    }
    *(float4*)(zx + (size_t)row * D_IN_PROJ + j0) = acc;
}

// ---------------------------------------------------------------------------
// Kernel 3: depthwise causal conv(4) + bias + SiLU; dt softplus; decay exp(dt*A)
__global__ void conv_dt_kernel(const float* __restrict__ zx,
                               const float* __restrict__ conv_w,
                               const float* __restrict__ conv_b,
                               const float* __restrict__ dt_bias,
                               const float* __restrict__ A_log,
                               float* __restrict__ xBC,
                               float* __restrict__ dtb,
                               float* __restrict__ dcb) {
    int bl = blockIdx.x;
    int l = bl & (SEQ - 1);
    int tid = threadIdx.x;
    const float* src = zx + (size_t)bl * D_IN_PROJ + D_INNER;
    if (tid < D_XBC) {
        float w0 = conv_w[tid*4+0], w1 = conv_w[tid*4+1];
        float w2 = conv_w[tid*4+2], w3 = conv_w[tid*4+3];
        float acc = conv_b[tid] + src[tid] * w3;
        if (l >= 1) acc += src[tid - 1*D_IN_PROJ] * w2;
        if (l >= 2) acc += src[tid - 2*D_IN_PROJ] * w1;
        if (l >= 3) acc += src[tid - 3*D_IN_PROJ] * w0;
        float s = acc / (1.f + expf(-acc));      // SiLU
        xBC[(size_t)bl * D_XBC + tid] = s;
    } else if (tid < D_XBC + NHEADS) {
        int h = tid - D_XBC;
        float v = zx[(size_t)bl * D_IN_PROJ + 320 + h] + dt_bias[h];
        float dtv = (v > 20.f) ? v : log1pf(expf(v));
        dtb[(size_t)bl * NHEADS + h] = dtv;
        float A = -expf(A_log[h]);
        dcb[(size_t)bl * NHEADS + h] = expf(dtv * A);
    }
}

// ---------------------------------------------------------------------------
// Chunked scan, phase 1: per (b,h,chunk) run the recurrence with s0=0;
// emit final chunk state (32x32) and scalar decay product P of the chunk.
__global__ __launch_bounds__(256) void scan_phase1_kernel(
        const float* __restrict__ xBC, const float* __restrict__ dtb,
        const float* __restrict__ dcb,
        float* __restrict__ sbuf, float* __restrict__ Pbuf) {
    int c  = blockIdx.x & (NCHUNK - 1);
    int bh = blockIdx.x >> 5;
    int b = bh >> 2, h = bh & 3;
    int tid = threadIdx.x;
    int p  = tid >> 3;
    int nb = (tid & 7) * 4;
    float4 s = make_float4(0.f, 0.f, 0.f, 0.f);
    float pacc = 1.f;
    const float* xc  = xBC + (size_t)b * SEQ * D_XBC;
    const float* dtp = dtb + (size_t)b * SEQ * NHEADS + h;
    const float* dcp = dcb + (size_t)b * SEQ * NHEADS + h;
    int l0 = c * CLEN;
#pragma unroll 4
    for (int i = 0; i < CLEN; ++i) {
        int l = l0 + i;
        float dtv = dtp[l * NHEADS];
        float dec = dcp[l * NHEADS];
        const float* rowp = xc + (size_t)l * D_XBC;
        float xv = rowp[h * HEADDIM + p];
        float4 Bv = *(const float4*)(rowp + D_INNER + nb);
        float coef = dtv * xv;
        s.x = s.x * dec + coef * Bv.x;
        s.y = s.y * dec + coef * Bv.y;
        s.z = s.z * dec + coef * Bv.z;
        s.w = s.w * dec + coef * Bv.w;
        pacc *= dec;
    }
    ((float4*)sbuf)[(size_t)(bh * NCHUNK + c) * 256 + tid] = s;
    if (tid == 0) Pbuf[bh * NCHUNK + c] = pacc;
}

// ---------------------------------------------------------------------------
// Phase 2: per (b,h) sequentially combine chunk states; overwrite sbuf[c]
// with the INITIAL state for chunk c.
__global__ __launch_bounds__(256) void scan_phase2_kernel(
        float* __restrict__ sbuf, const float* __restrict__ Pbuf) {
    int bh = blockIdx.x;
    int tid = threadIdx.x;
    float4 run = make_float4(0.f, 0.f, 0.f, 0.f);
    float4* sb = (float4*)sbuf + (size_t)bh * NCHUNK * 256 + tid;
    for (int c = 0; c < NCHUNK; ++c) {
        float4 tmp = sb[(size_t)c * 256];
        float Pv = Pbuf[bh * NCHUNK + c];
        sb[(size_t)c * 256] = run;
        run.x = run.x * Pv + tmp.x;
        run.y = run.y * Pv + tmp.y;
        run.z = run.z * Pv + tmp.z;
        run.w = run.w * Pv + tmp.w;
    }
}

// ---------------------------------------------------------------------------
// Phase 3: per (b,h,chunk) re-run the recurrence seeded with the correct
// initial state, producing y.
__global__ __launch_bounds__(256) void scan_phase3_kernel(
        const float* __restrict__ xBC, const float* __restrict__ dtb,
        const float* __restrict__ dcb, const float* __restrict__ Dp,
        const float* __restrict__ sbuf, float* __restrict__ yraw) {
    int c  = blockIdx.x & (NCHUNK - 1);
    int bh = blockIdx.x >> 5;
    int b = bh >> 2, h = bh & 3;
    int tid = threadIdx.x;
    int p  = tid >> 3;
    int nb = (tid & 7) * 4;
    float Dh = Dp[h];
    float4 s = ((const float4*)sbuf)[(size_t)(bh * NCHUNK + c) * 256 + tid];
    const float* xc  = xBC + (size_t)b * SEQ * D_XBC;
    const float* dtp = dtb + (size_t)b * SEQ * NHEADS + h;
    const float* dcp = dcb + (size_t)b * SEQ * NHEADS + h;
    float* yp = yraw + (size_t)b * SEQ * D_INNER + h * HEADDIM + p;
    int l0 = c * CLEN;
#pragma unroll 2
    for (int i = 0; i < CLEN; ++i) {
        int l = l0 + i;
        float dtv = dtp[l * NHEADS];
        float dec = dcp[l * NHEADS];
        const float* rowp = xc + (size_t)l * D_XBC;
        float xv = rowp[h * HEADDIM + p];
        float4 Bv = *(const float4*)(rowp + D_INNER + nb);
        float4 Cv = *(const float4*)(rowp + D_INNER + D_STATE + nb);
        float coef = dtv * xv;
        s.x = s.x * dec + coef * Bv.x;
        s.y = s.y * dec + coef * Bv.y;
        s.z = s.z * dec + coef * Bv.z;
        s.w = s.w * dec + coef * Bv.w;
        float part = s.x*Cv.x + s.y*Cv.y + s.z*Cv.z + s.w*Cv.w;
        part += __shfl_xor(part, 1);
        part += __shfl_xor(part, 2);
        part += __shfl_xor(part, 4);
        if ((tid & 7) == 0) yp[(size_t)l * D_INNER] = part + Dh * xv;
    }
}

// ---------------------------------------------------------------------------
// Kernel 5: gate*silu(z) + RMSNorm, accumulate G[b][i] = sum_l gn[b,l,i].
// Grid: 16 b * 32 chunks; 256 threads = 4 waves; one wave per row (l).
// Lane owns channels 2*lane, 2*lane+1 (float2, coalesced).
__global__ __launch_bounds__(256) void gate_acc_kernel(
        const float* __restrict__ yraw, const float* __restrict__ zx,
        const float* __restrict__ norm_w, float* __restrict__ G) {
    int b = blockIdx.x >> 5;
    int c = blockIdx.x & 31;
    int wave = threadIdx.x >> 6;
    int lane = threadIdx.x & 63;
    float acc0 = 0.f, acc1 = 0.f;
    int l0 = c * 64;
    for (int li = wave; li < 64; li += 4) {
        size_t bl = (size_t)b * SEQ + l0 + li;
        float2 yv = *(const float2*)(yraw + bl * D_INNER + lane * 2);
        float2 zv = *(const float2*)(zx + bl * D_IN_PROJ + lane * 2);
        float g0 = yv.x * (zv.x / (1.f + expf(-zv.x)));
        float g1 = yv.y * (zv.y / (1.f + expf(-zv.y)));
        float sq = g0 * g0 + g1 * g1;
#pragma unroll
        for (int m = 1; m < 64; m <<= 1) sq += __shfl_xor(sq, m);
        float rms = 1.0f / sqrtf(sq * (1.f / 128.f) + 1e-5f);
        acc0 += g0 * rms;
        acc1 += g1 * rms;
    }
    // combine 4 waves in LDS, then 128 atomicAdds per block
    __shared__ float red[4][D_INNER];
    red[wave][lane * 2]     = acc0;
    red[wave][lane * 2 + 1] = acc1;
    __syncthreads();
    int tid = threadIdx.x;
    if (tid < D_INNER) {
        float s = red[0][tid] + red[1][tid] + red[2][tid] + red[3][tid];
        atomicAdd(&G[b * D_INNER + tid], s * norm_w[tid]);
    }
}

// ---------------------------------------------------------------------------
// Kernel 6: out[b][o] = b_cls[o] + (G[b] @ W_oc)[o] / SEQ
__global__ void head_kernel(const float* __restrict__ G,
                            const float* __restrict__ Woc,
                            const float* __restrict__ b_cls,
                            float* __restrict__ out) {
    int tid = threadIdx.x;
    if (tid >= BATCH * OUT_DIM) return;
    int b = tid / OUT_DIM, o = tid - b * OUT_DIM;
    float acc = 0.f;
#pragma unroll 8
    for (int i = 0; i < D_INNER; ++i)
        acc += G[b * D_INNER + i] * Woc[i * OUT_DIM + o];
    out[b * OUT_DIM + o] = acc * (1.f / (float)SEQ) + b_cls[o];
}

// ---------------------------------------------------------------------------
extern "C" void kernel_launch(void* const* d_in, const int* in_sizes, int n_in,
                              void* d_out, int out_size, void* d_ws, size_t ws_size,
                              hipStream_t stream) {
    const float* x       = (const float*)d_in[0];
    const float* W_lin   = (const float*)d_in[1];
    const float* b_lin   = (const float*)d_in[2];
    const float* W_in    = (const float*)d_in[3];
    const float* conv_w  = (const float*)d_in[4];
    const float* conv_b  = (const float*)d_in[5];
    const float* dt_bias = (const float*)d_in[6];
    const float* A_log   = (const float*)d_in[7];
    const float* Dp      = (const float*)d_in[8];
    const float* norm_w  = (const float*)d_in[9];
    const float* W_out   = (const float*)d_in[10];
    const float* W_cls   = (const float*)d_in[11];
    const float* b_cls   = (const float*)d_in[12];
    float* out = (float*)d_out;

    float* ws = (float*)d_ws;
    float* Wf   = ws + OFF_WF;
    float* bf   = ws + OFF_BF;
    float* zx   = ws + OFF_ZX;
    float* xBC  = ws + OFF_XBC;
    float* dtb  = ws + OFF_DT;
    float* dcb  = ws + OFF_DEC;
    float* yraw = ws + OFF_Y;
    float* G    = ws + OFF_G;
    float* Woc  = ws + OFF_WOC;
    float* sbuf = ws + OFF_SB;
    float* Pbuf = ws + OFF_P;

    // zero the G accumulator (ws is poisoned before every call)
    hipMemsetAsync(G, 0, BATCH * D_INNER * sizeof(float), stream);

    // 1) fused weight precompute: 58*324 + 128*6 = 19560 threads
    fuse_w_kernel<<<(58 * D_IN_PROJ + D_INNER * OUT_DIM + 255) / 256, 256, 0, stream>>>(
        W_lin, b_lin, W_in, W_out, W_cls, Wf, bf, Woc);

    // 2) in-projection
    inproj_kernel<<<(BL * 81) / 256, 256, 0, stream>>>(x, Wf, bf, zx);

    // 3) conv + dt/decay
    conv_dt_kernel<<<BL, 256, 0, stream>>>(zx, conv_w, conv_b, dt_bias, A_log, xBC, dtb, dcb);

    // 4) chunked selective scan
    scan_phase1_kernel<<<BATCH * NHEADS * NCHUNK, 256, 0, stream>>>(xBC, dtb, dcb, sbuf, Pbuf);
    scan_phase2_kernel<<<BATCH * NHEADS, 256, 0, stream>>>(sbuf, Pbuf);
    scan_phase3_kernel<<<BATCH * NHEADS * NCHUNK, 256, 0, stream>>>(xBC, dtb, dcb, Dp, sbuf, yraw);

    // 5) gate + RMSNorm + channel accumulation
    gate_acc_kernel<<<BATCH * 32, 256, 0, stream>>>(yraw, zx, norm_w, G);

    // 6) classifier head (G @ (W_out@W_cls) / SEQ + b_cls)
    head_kernel<<<1, 128, 0, stream>>>(G, Woc, b_cls, out);
}

// Round 5
// 268.381 us; speedup vs baseline: 4.5121x; 1.1078x over previous
//
#include <hip/hip_runtime.h>
#include <hip/hip_bf16.h>
#include <cmath>

// Problem constants
#define BATCH   16
#define SEQ     2048
#define IN_DIM  57
#define D_MODEL 64
#define HEADDIM 32
#define D_STATE 32
#define OUT_DIM 6
#define D_INNER 128
#define NHEADS  4
#define D_CONV  4
#define D_XBC   192          // D_INNER + 2*D_STATE
#define D_IN_PROJ 324        // 2*D_INNER + 2*D_STATE + NHEADS
#define BL      (BATCH*SEQ)  // 32768

// Chunked scan config
#define NCHUNK  32
#define CLEN    (SEQ / NCHUNK)   // 64

// inproj row blocking
#define RPT 8                    // rows per thread

// Workspace layout (floats)
#define OFF_WF   ((size_t)0)                       // 57*324
#define OFF_BF   ((size_t)18496)                   // 324
#define OFF_ZX   ((size_t)18848)                   // BL*324
#define OFF_XBC  (OFF_ZX  + (size_t)BL*D_IN_PROJ)  // BL*192
#define OFF_DT   (OFF_XBC + (size_t)BL*D_XBC)      // BL*4
#define OFF_DEC  (OFF_DT  + (size_t)BL*NHEADS)     // BL*4
#define OFF_Y    (OFF_DEC + (size_t)BL*NHEADS)     // BL*128
#define OFF_G    (OFF_Y   + (size_t)BL*D_INNER)    // 16*128 = 2048
#define OFF_WOC  (OFF_G   + (size_t)2048)          // 128*6 = 768 (pad 896)
#define OFF_SB   (OFF_WOC + (size_t)896)           // 64*32*1024 chunk states
#define OFF_P    (OFF_SB  + (size_t)64*NCHUNK*1024)// 64*32 decay products
// total ~ 23.5M floats ~ 94 MB

// ---------------------------------------------------------------------------
// Kernel 1: Wf = W_lin@W_in ; bf = b_lin@W_in ; W_oc = W_out@W_cls
__global__ void fuse_w_kernel(const float* __restrict__ W_lin,
                              const float* __restrict__ b_lin,
                              const float* __restrict__ W_in,
                              const float* __restrict__ W_out,
                              const float* __restrict__ W_cls,
                              float* __restrict__ Wf, float* __restrict__ bf,
                              float* __restrict__ Woc) {
    int idx = blockIdx.x * 256 + threadIdx.x;
    if (idx < 58 * D_IN_PROJ) {
        int r = idx / D_IN_PROJ;
        int j = idx - r * D_IN_PROJ;
        const float* v = (r < IN_DIM) ? (W_lin + r * D_MODEL) : b_lin;
        float acc = 0.f;
#pragma unroll 8
        for (int m = 0; m < D_MODEL; ++m) acc += v[m] * W_in[m * D_IN_PROJ + j];
        if (r < IN_DIM) Wf[r * D_IN_PROJ + j] = acc;
        else            bf[j] = acc;
    } else if (idx < 58 * D_IN_PROJ + D_INNER * OUT_DIM) {
        int idx2 = idx - 58 * D_IN_PROJ;
        int i = idx2 / OUT_DIM;
        int o = idx2 - i * OUT_DIM;
        float acc = 0.f;
#pragma unroll 8
        for (int j = 0; j < D_MODEL; ++j)
            acc += W_out[i * D_MODEL + j] * W_cls[j * OUT_DIM + o];
        Woc[i * OUT_DIM + o] = acc;
    }
}

// ---------------------------------------------------------------------------
// Kernel 2: register-blocked in-projection. Thread handles RPT rows x 4 cols.
// One weight float4 load feeds 4*RPT FMAs (weight cache traffic / RPT).
__global__ __launch_bounds__(256) void inproj_kernel(
        const float* __restrict__ x,
        const float* __restrict__ Wf,
        const float* __restrict__ bf,
        float* __restrict__ zx) {
    int gid = blockIdx.x * 256 + threadIdx.x;   // (BL/RPT)*81 threads exactly
    int rg = gid / 81;
    int cg = gid - rg * 81;
    int j0 = cg * 4;
    const float* xr = x + (size_t)rg * RPT * IN_DIM;
    float4 bias = *(const float4*)(bf + j0);
    float4 acc[RPT];
#pragma unroll
    for (int r = 0; r < RPT; ++r) acc[r] = bias;
    const float* w = Wf + j0;
    for (int k = 0; k < IN_DIM; ++k) {
        float4 wv = *(const float4*)(w + (size_t)k * D_IN_PROJ);
#pragma unroll
        for (int r = 0; r < RPT; ++r) {
            float xv = xr[r * IN_DIM + k];
            acc[r].x += xv * wv.x; acc[r].y += xv * wv.y;
            acc[r].z += xv * wv.z; acc[r].w += xv * wv.w;
        }
    }
#pragma unroll
    for (int r = 0; r < RPT; ++r)
        *(float4*)(zx + (size_t)(rg * RPT + r) * D_IN_PROJ + j0) = acc[r];
}

// ---------------------------------------------------------------------------
// Kernel 3: depthwise causal conv(4) + bias + SiLU; dt softplus; decay exp(dt*A).
// One block per (b, chunk of 64 rows); channel threads keep a sliding window
// of their last 3 inputs in registers -> each zx value read exactly once.
__global__ __launch_bounds__(256) void conv_dt_kernel(
        const float* __restrict__ zx,
        const float* __restrict__ conv_w,
        const float* __restrict__ conv_b,
        const float* __restrict__ dt_bias,
        const float* __restrict__ A_log,
        float* __restrict__ xBC,
        float* __restrict__ dtb,
        float* __restrict__ dcb) {
    int b = blockIdx.x >> 5;        // 32 chunks of 64
    int c = blockIdx.x & 31;
    int l0 = c * 64;
    int tid = threadIdx.x;
    size_t bl0 = (size_t)b * SEQ + l0;
    if (tid < D_XBC) {
        float w0 = conv_w[tid*4+0], w1 = conv_w[tid*4+1];
        float w2 = conv_w[tid*4+2], w3 = conv_w[tid*4+3];
        float cb = conv_b[tid];
        const float* src = zx + bl0 * D_IN_PROJ + D_INNER + tid;
        float vm1 = 0.f, vm2 = 0.f, vm3 = 0.f;
        if (c > 0) {
            vm1 = src[-(int)D_IN_PROJ];
            vm2 = src[-2*(int)D_IN_PROJ];
            vm3 = src[-3*(int)D_IN_PROJ];
        }
        float* dst = xBC + bl0 * D_XBC + tid;
#pragma unroll 4
        for (int i = 0; i < 64; ++i) {
            float v0 = src[(size_t)i * D_IN_PROJ];
            float a = cb + v0 * w3 + vm1 * w2 + vm2 * w1 + vm3 * w0;
            dst[(size_t)i * D_XBC] = a / (1.f + expf(-a));   // SiLU
            vm3 = vm2; vm2 = vm1; vm1 = v0;
        }
    } else if (tid < D_XBC + NHEADS) {
        int h = tid - D_XBC;
        float bias = dt_bias[h];
        float A = -expf(A_log[h]);
        const float* src = zx + bl0 * D_IN_PROJ + 320 + h;
        float* dt_dst = dtb + bl0 * NHEADS + h;
        float* dc_dst = dcb + bl0 * NHEADS + h;
        for (int i = 0; i < 64; ++i) {
            float v = src[(size_t)i * D_IN_PROJ] + bias;
            float dtv = (v > 20.f) ? v : log1pf(expf(v));
            dt_dst[(size_t)i * NHEADS] = dtv;
            dc_dst[(size_t)i * NHEADS] = expf(dtv * A);
        }
    }
}

// ---------------------------------------------------------------------------
// Chunked scan, phase 1: per (b,h,chunk) run the recurrence with s0=0;
// emit final chunk state (32x32) and scalar decay product P of the chunk.
__global__ __launch_bounds__(256) void scan_phase1_kernel(
        const float* __restrict__ xBC, const float* __restrict__ dtb,
        const float* __restrict__ dcb,
        float* __restrict__ sbuf, float* __restrict__ Pbuf) {
    int c  = blockIdx.x & (NCHUNK - 1);
    int bh = blockIdx.x >> 5;
    int b = bh >> 2, h = bh & 3;
    int tid = threadIdx.x;
    int p  = tid >> 3;
    int nb = (tid & 7) * 4;
    float4 s = make_float4(0.f, 0.f, 0.f, 0.f);
    float pacc = 1.f;
    const float* xc  = xBC + (size_t)b * SEQ * D_XBC;
    const float* dtp = dtb + (size_t)b * SEQ * NHEADS + h;
    const float* dcp = dcb + (size_t)b * SEQ * NHEADS + h;
    int l0 = c * CLEN;
#pragma unroll 4
    for (int i = 0; i < CLEN; ++i) {
        int l = l0 + i;
        float dtv = dtp[l * NHEADS];
        float dec = dcp[l * NHEADS];
        const float* rowp = xc + (size_t)l * D_XBC;
        float xv = rowp[h * HEADDIM + p];
        float4 Bv = *(const float4*)(rowp + D_INNER + nb);
        float coef = dtv * xv;
        s.x = s.x * dec + coef * Bv.x;
        s.y = s.y * dec + coef * Bv.y;
        s.z = s.z * dec + coef * Bv.z;
        s.w = s.w * dec + coef * Bv.w;
        pacc *= dec;
    }
    ((float4*)sbuf)[(size_t)(bh * NCHUNK + c) * 256 + tid] = s;
    if (tid == 0) Pbuf[bh * NCHUNK + c] = pacc;
}

// ---------------------------------------------------------------------------
// Phase 2: per (b,h) sequentially combine chunk states; overwrite sbuf[c]
// with the INITIAL state for chunk c.
__global__ __launch_bounds__(256) void scan_phase2_kernel(
        float* __restrict__ sbuf, const float* __restrict__ Pbuf) {
    int bh = blockIdx.x;
    int tid = threadIdx.x;
    float4 run = make_float4(0.f, 0.f, 0.f, 0.f);
    float4* sb = (float4*)sbuf + (size_t)bh * NCHUNK * 256 + tid;
    for (int c = 0; c < NCHUNK; ++c) {
        float4 tmp = sb[(size_t)c * 256];
        float Pv = Pbuf[bh * NCHUNK + c];
        sb[(size_t)c * 256] = run;
        run.x = run.x * Pv + tmp.x;
        run.y = run.y * Pv + tmp.y;
        run.z = run.z * Pv + tmp.z;
        run.w = run.w * Pv + tmp.w;
    }
}

// ---------------------------------------------------------------------------
// Phase 3: per (b,h,chunk) re-run the recurrence seeded with the correct
// initial state, producing y.
__global__ __launch_bounds__(256) void scan_phase3_kernel(
        const float* __restrict__ xBC, const float* __restrict__ dtb,
        const float* __restrict__ dcb, const float* __restrict__ Dp,
        const float* __restrict__ sbuf, float* __restrict__ yraw) {
    int c  = blockIdx.x & (NCHUNK - 1);
    int bh = blockIdx.x >> 5;
    int b = bh >> 2, h = bh & 3;
    int tid = threadIdx.x;
    int p  = tid >> 3;
    int nb = (tid & 7) * 4;
    float Dh = Dp[h];
    float4 s = ((const float4*)sbuf)[(size_t)(bh * NCHUNK + c) * 256 + tid];
    const float* xc  = xBC + (size_t)b * SEQ * D_XBC;
    const float* dtp = dtb + (size_t)b * SEQ * NHEADS + h;
    const float* dcp = dcb + (size_t)b * SEQ * NHEADS + h;
    float* yp = yraw + (size_t)b * SEQ * D_INNER + h * HEADDIM + p;
    int l0 = c * CLEN;
#pragma unroll 2
    for (int i = 0; i < CLEN; ++i) {
        int l = l0 + i;
        float dtv = dtp[l * NHEADS];
        float dec = dcp[l * NHEADS];
        const float* rowp = xc + (size_t)l * D_XBC;
        float xv = rowp[h * HEADDIM + p];
        float4 Bv = *(const float4*)(rowp + D_INNER + nb);
        float4 Cv = *(const float4*)(rowp + D_INNER + D_STATE + nb);
        float coef = dtv * xv;
        s.x = s.x * dec + coef * Bv.x;
        s.y = s.y * dec + coef * Bv.y;
        s.z = s.z * dec + coef * Bv.z;
        s.w = s.w * dec + coef * Bv.w;
        float part = s.x*Cv.x + s.y*Cv.y + s.z*Cv.z + s.w*Cv.w;
        part += __shfl_xor(part, 1);
        part += __shfl_xor(part, 2);
        part += __shfl_xor(part, 4);
        if ((tid & 7) == 0) yp[(size_t)l * D_INNER] = part + Dh * xv;
    }
}

// ---------------------------------------------------------------------------
// Kernel 5: gate*silu(z) + RMSNorm, accumulate G[b][i] = sum_l gn[b,l,i].
__global__ __launch_bounds__(256) void gate_acc_kernel(
        const float* __restrict__ yraw, const float* __restrict__ zx,
        const float* __restrict__ norm_w, float* __restrict__ G) {
    int b = blockIdx.x >> 5;
    int c = blockIdx.x & 31;
    int wave = threadIdx.x >> 6;
    int lane = threadIdx.x & 63;
    float acc0 = 0.f, acc1 = 0.f;
    int l0 = c * 64;
    for (int li = wave; li < 64; li += 4) {
        size_t bl = (size_t)b * SEQ + l0 + li;
        float2 yv = *(const float2*)(yraw + bl * D_INNER + lane * 2);
        float2 zv = *(const float2*)(zx + bl * D_IN_PROJ + lane * 2);
        float g0 = yv.x * (zv.x / (1.f + expf(-zv.x)));
        float g1 = yv.y * (zv.y / (1.f + expf(-zv.y)));
        float sq = g0 * g0 + g1 * g1;
#pragma unroll
        for (int m = 1; m < 64; m <<= 1) sq += __shfl_xor(sq, m);
        float rms = 1.0f / sqrtf(sq * (1.f / 128.f) + 1e-5f);
        acc0 += g0 * rms;
        acc1 += g1 * rms;
    }
    __shared__ float red[4][D_INNER];
    red[wave][lane * 2]     = acc0;
    red[wave][lane * 2 + 1] = acc1;
    __syncthreads();
    int tid = threadIdx.x;
    if (tid < D_INNER) {
        float s = red[0][tid] + red[1][tid] + red[2][tid] + red[3][tid];
        atomicAdd(&G[b * D_INNER + tid], s * norm_w[tid]);
    }
}

// ---------------------------------------------------------------------------
// Kernel 6: out[b][o] = b_cls[o] + (G[b] @ W_oc)[o] / SEQ
__global__ void head_kernel(const float* __restrict__ G,
                            const float* __restrict__ Woc,
                            const float* __restrict__ b_cls,
                            float* __restrict__ out) {
    int tid = threadIdx.x;
    if (tid >= BATCH * OUT_DIM) return;
    int b = tid / OUT_DIM, o = tid - b * OUT_DIM;
    float acc = 0.f;
#pragma unroll 8
    for (int i = 0; i < D_INNER; ++i)
        acc += G[b * D_INNER + i] * Woc[i * OUT_DIM + o];
    out[b * OUT_DIM + o] = acc * (1.f / (float)SEQ) + b_cls[o];
}

// ---------------------------------------------------------------------------
extern "C" void kernel_launch(void* const* d_in, const int* in_sizes, int n_in,
                              void* d_out, int out_size, void* d_ws, size_t ws_size,
                              hipStream_t stream) {
    const float* x       = (const float*)d_in[0];
    const float* W_lin   = (const float*)d_in[1];
    const float* b_lin   = (const float*)d_in[2];
    const float* W_in    = (const float*)d_in[3];
    const float* conv_w  = (const float*)d_in[4];
    const float* conv_b  = (const float*)d_in[5];
    const float* dt_bias = (const float*)d_in[6];
    const float* A_log   = (const float*)d_in[7];
    const float* Dp      = (const float*)d_in[8];
    const float* norm_w  = (const float*)d_in[9];
    const float* W_out   = (const float*)d_in[10];
    const float* W_cls   = (const float*)d_in[11];
    const float* b_cls   = (const float*)d_in[12];
    float* out = (float*)d_out;

    float* ws = (float*)d_ws;
    float* Wf   = ws + OFF_WF;
    float* bf   = ws + OFF_BF;
    float* zx   = ws + OFF_ZX;
    float* xBC  = ws + OFF_XBC;
    float* dtb  = ws + OFF_DT;
    float* dcb  = ws + OFF_DEC;
    float* yraw = ws + OFF_Y;
    float* G    = ws + OFF_G;
    float* Woc  = ws + OFF_WOC;
    float* sbuf = ws + OFF_SB;
    float* Pbuf = ws + OFF_P;

    // zero the G accumulator (ws is poisoned before every call)
    hipMemsetAsync(G, 0, BATCH * D_INNER * sizeof(float), stream);

    // 1) fused weight precompute
    fuse_w_kernel<<<(58 * D_IN_PROJ + D_INNER * OUT_DIM + 255) / 256, 256, 0, stream>>>(
        W_lin, b_lin, W_in, W_out, W_cls, Wf, bf, Woc);

    // 2) in-projection (register-blocked, RPT rows/thread)
    inproj_kernel<<<(BL / RPT) * 81 / 256, 256, 0, stream>>>(x, Wf, bf, zx);

    // 3) conv + dt/decay: one block per (b, 64-row chunk)
    conv_dt_kernel<<<BATCH * 32, 256, 0, stream>>>(zx, conv_w, conv_b, dt_bias, A_log, xBC, dtb, dcb);

    // 4) chunked selective scan
    scan_phase1_kernel<<<BATCH * NHEADS * NCHUNK, 256, 0, stream>>>(xBC, dtb, dcb, sbuf, Pbuf);
    scan_phase2_kernel<<<BATCH * NHEADS, 256, 0, stream>>>(sbuf, Pbuf);
    scan_phase3_kernel<<<BATCH * NHEADS * NCHUNK, 256, 0, stream>>>(xBC, dtb, dcb, Dp, sbuf, yraw);

    // 5) gate + RMSNorm + channel accumulation
    gate_acc_kernel<<<BATCH * 32, 256, 0, stream>>>(yraw, zx, norm_w, G);

    // 6) classifier head (G @ (W_out@W_cls) / SEQ + b_cls)
    head_kernel<<<1, 128, 0, stream>>>(G, Woc, b_cls, out);
}

// Round 6
// 217.655 us; speedup vs baseline: 5.5637x; 1.2331x over previous
//
#include <hip/hip_runtime.h>
#include <hip/hip_bf16.h>
#include <cmath>

// Problem constants
#define BATCH   16
#define SEQ     2048
#define IN_DIM  57
#define D_MODEL 64
#define HEADDIM 32
#define D_STATE 32
#define OUT_DIM 6
#define D_INNER 128
#define NHEADS  4
#define D_CONV  4
#define D_XBC   192          // D_INNER + 2*D_STATE
#define D_IN_PROJ 324        // 2*D_INNER + 2*D_STATE + NHEADS
#define BL      (BATCH*SEQ)  // 32768

// Chunked scan config
#define NCHUNK  32
#define CLEN    (SEQ / NCHUNK)   // 64

// inproj tiling: 24 rows/block, thread = (rset 0..2) x (cg 0..80), 8 rows x 4 cols
#define RTILE   24
#define XPAD    60               // LDS row stride (floats): 240B, 16B-aligned

// conv_dt chunking
#define CCH     16               // rows per block

// Workspace layout (floats)
#define OFF_WF   ((size_t)0)                       // 57*324
#define OFF_BF   ((size_t)18496)                   // 324
#define OFF_ZX   ((size_t)18848)                   // BL*324
#define OFF_XBC  (OFF_ZX  + (size_t)BL*D_IN_PROJ)  // BL*192
#define OFF_DT   (OFF_XBC + (size_t)BL*D_XBC)      // BL*4
#define OFF_DEC  (OFF_DT  + (size_t)BL*NHEADS)     // BL*4
#define OFF_Y    (OFF_DEC + (size_t)BL*NHEADS)     // BL*128
#define OFF_G    (OFF_Y   + (size_t)BL*D_INNER)    // 16*128 = 2048
#define OFF_WOC  (OFF_G   + (size_t)2048)          // 128*6 (pad 896)
#define OFF_SB   (OFF_WOC + (size_t)896)           // 64*32*1024 chunk states
#define OFF_P    (OFF_SB  + (size_t)64*NCHUNK*1024)// 64*32 decay products

// ---------------------------------------------------------------------------
// Kernel 1: Wf = W_lin@W_in ; bf = b_lin@W_in ; W_oc = W_out@W_cls
__global__ void fuse_w_kernel(const float* __restrict__ W_lin,
                              const float* __restrict__ b_lin,
                              const float* __restrict__ W_in,
                              const float* __restrict__ W_out,
                              const float* __restrict__ W_cls,
                              float* __restrict__ Wf, float* __restrict__ bf,
                              float* __restrict__ Woc) {
    int idx = blockIdx.x * 256 + threadIdx.x;
    if (idx < 58 * D_IN_PROJ) {
        int r = idx / D_IN_PROJ;
        int j = idx - r * D_IN_PROJ;
        const float* v = (r < IN_DIM) ? (W_lin + r * D_MODEL) : b_lin;
        float acc = 0.f;
#pragma unroll 8
        for (int m = 0; m < D_MODEL; ++m) acc += v[m] * W_in[m * D_IN_PROJ + j];
        if (r < IN_DIM) Wf[r * D_IN_PROJ + j] = acc;
        else            bf[j] = acc;
    } else if (idx < 58 * D_IN_PROJ + D_INNER * OUT_DIM) {
        int idx2 = idx - 58 * D_IN_PROJ;
        int i = idx2 / OUT_DIM;
        int o = idx2 - i * OUT_DIM;
        float acc = 0.f;
#pragma unroll 8
        for (int j = 0; j < D_MODEL; ++j)
            acc += W_out[i * D_MODEL + j] * W_cls[j * OUT_DIM + o];
        Woc[i * OUT_DIM + o] = acc;
    }
}

// ---------------------------------------------------------------------------
// Kernel 2: LDS-staged in-projection. Block: 24 rows x 324 cols.
// Thread (rset = tid/81, cg = tid%81): 8 rows x 4 cols; x via ds_read_b128.
__global__ __launch_bounds__(256) void inproj_kernel(
        const float* __restrict__ x,
        const float* __restrict__ Wf,
        const float* __restrict__ bf,
        float* __restrict__ zx) {
    __shared__ float xs[RTILE][XPAD];
    int r0 = blockIdx.x * RTILE;
    // cooperative staging: x rows are contiguous, so linear index works
    for (int i = threadIdx.x; i < RTILE * IN_DIM; i += 256) {
        size_t g = (size_t)r0 * IN_DIM + i;
        float v = (g < (size_t)BL * IN_DIM) ? x[g] : 0.f;
        xs[i / IN_DIM][i % IN_DIM] = v;
    }
    __syncthreads();
    if (threadIdx.x >= 243) return;
    int rset = threadIdx.x / 81;          // 0..2
    int cg   = threadIdx.x - rset * 81;   // 0..80
    int j0   = cg * 4;
    float4 bias = *(const float4*)(bf + j0);
    float4 acc[8];
#pragma unroll
    for (int r = 0; r < 8; ++r) acc[r] = bias;
    const float* w = Wf + j0;
    const float* xrow = &xs[rset * 8][0];
#pragma unroll 2
    for (int kc = 0; kc < 14; ++kc) {
        int k = kc * 4;
        float4 wv0 = *(const float4*)(w + (size_t)(k + 0) * D_IN_PROJ);
        float4 wv1 = *(const float4*)(w + (size_t)(k + 1) * D_IN_PROJ);
        float4 wv2 = *(const float4*)(w + (size_t)(k + 2) * D_IN_PROJ);
        float4 wv3 = *(const float4*)(w + (size_t)(k + 3) * D_IN_PROJ);
#pragma unroll
        for (int r = 0; r < 8; ++r) {
            float4 xv = *(const float4*)(xrow + r * XPAD + k);
            acc[r].x += xv.x * wv0.x + xv.y * wv1.x + xv.z * wv2.x + xv.w * wv3.x;
            acc[r].y += xv.x * wv0.y + xv.y * wv1.y + xv.z * wv2.y + xv.w * wv3.y;
            acc[r].z += xv.x * wv0.z + xv.y * wv1.z + xv.z * wv2.z + xv.w * wv3.z;
            acc[r].w += xv.x * wv0.w + xv.y * wv1.w + xv.z * wv2.w + xv.w * wv3.w;
        }
    }
    { // k = 56
        float4 wv = *(const float4*)(w + (size_t)56 * D_IN_PROJ);
#pragma unroll
        for (int r = 0; r < 8; ++r) {
            float xv = xrow[r * XPAD + 56];
            acc[r].x += xv * wv.x; acc[r].y += xv * wv.y;
            acc[r].z += xv * wv.z; acc[r].w += xv * wv.w;
        }
    }
#pragma unroll
    for (int r = 0; r < 8; ++r) {
        int row = r0 + rset * 8 + r;
        if (row < BL)
            *(float4*)(zx + (size_t)row * D_IN_PROJ + j0) = acc[r];
    }
}

// ---------------------------------------------------------------------------
// Kernel 3: depthwise causal conv(4) + bias + SiLU; dt softplus; decay exp(dt*A).
// One block per (b, chunk of CCH rows); sliding window in registers.
__global__ __launch_bounds__(256) void conv_dt_kernel(
        const float* __restrict__ zx,
        const float* __restrict__ conv_w,
        const float* __restrict__ conv_b,
        const float* __restrict__ dt_bias,
        const float* __restrict__ A_log,
        float* __restrict__ xBC,
        float* __restrict__ dtb,
        float* __restrict__ dcb) {
    int b = blockIdx.x >> 7;          // SEQ/CCH = 128 chunks
    int c = blockIdx.x & 127;
    int l0 = c * CCH;
    int tid = threadIdx.x;
    size_t bl0 = (size_t)b * SEQ + l0;
    if (tid < D_XBC) {
        float w0 = conv_w[tid*4+0], w1 = conv_w[tid*4+1];
        float w2 = conv_w[tid*4+2], w3 = conv_w[tid*4+3];
        float cb = conv_b[tid];
        const float* src = zx + bl0 * D_IN_PROJ + D_INNER + tid;
        float vm1 = 0.f, vm2 = 0.f, vm3 = 0.f;
        if (c > 0) {
            vm1 = src[-(int)D_IN_PROJ];
            vm2 = src[-2*(int)D_IN_PROJ];
            vm3 = src[-3*(int)D_IN_PROJ];
        }
        float* dst = xBC + bl0 * D_XBC + tid;
#pragma unroll
        for (int i = 0; i < CCH; ++i) {
            float v0 = src[(size_t)i * D_IN_PROJ];
            float a = cb + v0 * w3 + vm1 * w2 + vm2 * w1 + vm3 * w0;
            dst[(size_t)i * D_XBC] = a / (1.f + expf(-a));   // SiLU
            vm3 = vm2; vm2 = vm1; vm1 = v0;
        }
    } else if (tid < D_XBC + NHEADS) {
        int h = tid - D_XBC;
        float bias = dt_bias[h];
        float A = -expf(A_log[h]);
        const float* src = zx + bl0 * D_IN_PROJ + 320 + h;
        float* dt_dst = dtb + bl0 * NHEADS + h;
        float* dc_dst = dcb + bl0 * NHEADS + h;
#pragma unroll
        for (int i = 0; i < CCH; ++i) {
            float v = src[(size_t)i * D_IN_PROJ] + bias;
            float dtv = (v > 20.f) ? v : log1pf(expf(v));
            dt_dst[(size_t)i * NHEADS] = dtv;
            dc_dst[(size_t)i * NHEADS] = expf(dtv * A);
        }
    }
}

// ---------------------------------------------------------------------------
// Chunked scan, phase 1: per (b,h,chunk) run the recurrence with s0=0;
// emit final chunk state (32x32) and scalar decay product P of the chunk.
__global__ __launch_bounds__(256) void scan_phase1_kernel(
        const float* __restrict__ xBC, const float* __restrict__ dtb,
        const float* __restrict__ dcb,
        float* __restrict__ sbuf, float* __restrict__ Pbuf) {
    int c  = blockIdx.x & (NCHUNK - 1);
    int bh = blockIdx.x >> 5;
    int b = bh >> 2, h = bh & 3;
    int tid = threadIdx.x;
    int p  = tid >> 3;
    int nb = (tid & 7) * 4;
    float4 s = make_float4(0.f, 0.f, 0.f, 0.f);
    float pacc = 1.f;
    const float* xc  = xBC + (size_t)b * SEQ * D_XBC;
    const float* dtp = dtb + (size_t)b * SEQ * NHEADS + h;
    const float* dcp = dcb + (size_t)b * SEQ * NHEADS + h;
    int l0 = c * CLEN;
#pragma unroll 4
    for (int i = 0; i < CLEN; ++i) {
        int l = l0 + i;
        float dtv = dtp[l * NHEADS];
        float dec = dcp[l * NHEADS];
        const float* rowp = xc + (size_t)l * D_XBC;
        float xv = rowp[h * HEADDIM + p];
        float4 Bv = *(const float4*)(rowp + D_INNER + nb);
        float coef = dtv * xv;
        s.x = s.x * dec + coef * Bv.x;
        s.y = s.y * dec + coef * Bv.y;
        s.z = s.z * dec + coef * Bv.z;
        s.w = s.w * dec + coef * Bv.w;
        pacc *= dec;
    }
    ((float4*)sbuf)[(size_t)(bh * NCHUNK + c) * 256 + tid] = s;
    if (tid == 0) Pbuf[bh * NCHUNK + c] = pacc;
}

// ---------------------------------------------------------------------------
// Phase 2: per (b,h) sequentially combine chunk states; overwrite sbuf[c]
// with the INITIAL state for chunk c.
__global__ __launch_bounds__(256) void scan_phase2_kernel(
        float* __restrict__ sbuf, const float* __restrict__ Pbuf) {
    int bh = blockIdx.x;
    int tid = threadIdx.x;
    float4 run = make_float4(0.f, 0.f, 0.f, 0.f);
    float4* sb = (float4*)sbuf + (size_t)bh * NCHUNK * 256 + tid;
    for (int c = 0; c < NCHUNK; ++c) {
        float4 tmp = sb[(size_t)c * 256];
        float Pv = Pbuf[bh * NCHUNK + c];
        sb[(size_t)c * 256] = run;
        run.x = run.x * Pv + tmp.x;
        run.y = run.y * Pv + tmp.y;
        run.z = run.z * Pv + tmp.z;
        run.w = run.w * Pv + tmp.w;
    }
}

// ---------------------------------------------------------------------------
// Phase 3: per (b,h,chunk) re-run the recurrence seeded with the correct
// initial state, producing y.
__global__ __launch_bounds__(256) void scan_phase3_kernel(
        const float* __restrict__ xBC, const float* __restrict__ dtb,
        const float* __restrict__ dcb, const float* __restrict__ Dp,
        const float* __restrict__ sbuf, float* __restrict__ yraw) {
    int c  = blockIdx.x & (NCHUNK - 1);
    int bh = blockIdx.x >> 5;
    int b = bh >> 2, h = bh & 3;
    int tid = threadIdx.x;
    int p  = tid >> 3;
    int nb = (tid & 7) * 4;
    float Dh = Dp[h];
    float4 s = ((const float4*)sbuf)[(size_t)(bh * NCHUNK + c) * 256 + tid];
    const float* xc  = xBC + (size_t)b * SEQ * D_XBC;
    const float* dtp = dtb + (size_t)b * SEQ * NHEADS + h;
    const float* dcp = dcb + (size_t)b * SEQ * NHEADS + h;
    float* yp = yraw + (size_t)b * SEQ * D_INNER + h * HEADDIM + p;
    int l0 = c * CLEN;
#pragma unroll 2
    for (int i = 0; i < CLEN; ++i) {
        int l = l0 + i;
        float dtv = dtp[l * NHEADS];
        float dec = dcp[l * NHEADS];
        const float* rowp = xc + (size_t)l * D_XBC;
        float xv = rowp[h * HEADDIM + p];
        float4 Bv = *(const float4*)(rowp + D_INNER + nb);
        float4 Cv = *(const float4*)(rowp + D_INNER + D_STATE + nb);
        float coef = dtv * xv;
        s.x = s.x * dec + coef * Bv.x;
        s.y = s.y * dec + coef * Bv.y;
        s.z = s.z * dec + coef * Bv.z;
        s.w = s.w * dec + coef * Bv.w;
        float part = s.x*Cv.x + s.y*Cv.y + s.z*Cv.z + s.w*Cv.w;
        part += __shfl_xor(part, 1);
        part += __shfl_xor(part, 2);
        part += __shfl_xor(part, 4);
        if ((tid & 7) == 0) yp[(size_t)l * D_INNER] = part + Dh * xv;
    }
}

// ---------------------------------------------------------------------------
// Kernel 5: gate*silu(z) + RMSNorm, accumulate G[b][i] = sum_l gn[b,l,i].
__global__ __launch_bounds__(256) void gate_acc_kernel(
        const float* __restrict__ yraw, const float* __restrict__ zx,
        const float* __restrict__ norm_w, float* __restrict__ G) {
    int b = blockIdx.x >> 5;
    int c = blockIdx.x & 31;
    int wave = threadIdx.x >> 6;
    int lane = threadIdx.x & 63;
    float acc0 = 0.f, acc1 = 0.f;
    int l0 = c * 64;
    for (int li = wave; li < 64; li += 4) {
        size_t bl = (size_t)b * SEQ + l0 + li;
        float2 yv = *(const float2*)(yraw + bl * D_INNER + lane * 2);
        float2 zv = *(const float2*)(zx + bl * D_IN_PROJ + lane * 2);
        float g0 = yv.x * (zv.x / (1.f + expf(-zv.x)));
        float g1 = yv.y * (zv.y / (1.f + expf(-zv.y)));
        float sq = g0 * g0 + g1 * g1;
#pragma unroll
        for (int m = 1; m < 64; m <<= 1) sq += __shfl_xor(sq, m);
        float rms = 1.0f / sqrtf(sq * (1.f / 128.f) + 1e-5f);
        acc0 += g0 * rms;
        acc1 += g1 * rms;
    }
    __shared__ float red[4][D_INNER];
    red[wave][lane * 2]     = acc0;
    red[wave][lane * 2 + 1] = acc1;
    __syncthreads();
    int tid = threadIdx.x;
    if (tid < D_INNER) {
        float s = red[0][tid] + red[1][tid] + red[2][tid] + red[3][tid];
        atomicAdd(&G[b * D_INNER + tid], s * norm_w[tid]);
    }
}

// ---------------------------------------------------------------------------
// Kernel 6: out[b][o] = b_cls[o] + (G[b] @ W_oc)[o] / SEQ
__global__ void head_kernel(const float* __restrict__ G,
                            const float* __restrict__ Woc,
                            const float* __restrict__ b_cls,
                            float* __restrict__ out) {
    int tid = threadIdx.x;
    if (tid >= BATCH * OUT_DIM) return;
    int b = tid / OUT_DIM, o = tid - b * OUT_DIM;
    float acc = 0.f;
#pragma unroll 8
    for (int i = 0; i < D_INNER; ++i)
        acc += G[b * D_INNER + i] * Woc[i * OUT_DIM + o];
    out[b * OUT_DIM + o] = acc * (1.f / (float)SEQ) + b_cls[o];
}

// ---------------------------------------------------------------------------
extern "C" void kernel_launch(void* const* d_in, const int* in_sizes, int n_in,
                              void* d_out, int out_size, void* d_ws, size_t ws_size,
                              hipStream_t stream) {
    const float* x       = (const float*)d_in[0];
    const float* W_lin   = (const float*)d_in[1];
    const float* b_lin   = (const float*)d_in[2];
    const float* W_in    = (const float*)d_in[3];
    const float* conv_w  = (const float*)d_in[4];
    const float* conv_b  = (const float*)d_in[5];
    const float* dt_bias = (const float*)d_in[6];
    const float* A_log   = (const float*)d_in[7];
    const float* Dp      = (const float*)d_in[8];
    const float* norm_w  = (const float*)d_in[9];
    const float* W_out   = (const float*)d_in[10];
    const float* W_cls   = (const float*)d_in[11];
    const float* b_cls   = (const float*)d_in[12];
    float* out = (float*)d_out;

    float* ws = (float*)d_ws;
    float* Wf   = ws + OFF_WF;
    float* bf   = ws + OFF_BF;
    float* zx   = ws + OFF_ZX;
    float* xBC  = ws + OFF_XBC;
    float* dtb  = ws + OFF_DT;
    float* dcb  = ws + OFF_DEC;
    float* yraw = ws + OFF_Y;
    float* G    = ws + OFF_G;
    float* Woc  = ws + OFF_WOC;
    float* sbuf = ws + OFF_SB;
    float* Pbuf = ws + OFF_P;

    // zero the G accumulator (ws is poisoned before every call)
    hipMemsetAsync(G, 0, BATCH * D_INNER * sizeof(float), stream);

    // 1) fused weight precompute
    fuse_w_kernel<<<(58 * D_IN_PROJ + D_INNER * OUT_DIM + 255) / 256, 256, 0, stream>>>(
        W_lin, b_lin, W_in, W_out, W_cls, Wf, bf, Woc);

    // 2) in-projection (LDS-staged, 24 rows/block)
    inproj_kernel<<<(BL + RTILE - 1) / RTILE, 256, 0, stream>>>(x, Wf, bf, zx);

    // 3) conv + dt/decay: one block per (b, 16-row chunk) = 2048 blocks
    conv_dt_kernel<<<BATCH * (SEQ / CCH), 256, 0, stream>>>(zx, conv_w, conv_b, dt_bias, A_log, xBC, dtb, dcb);

    // 4) chunked selective scan
    scan_phase1_kernel<<<BATCH * NHEADS * NCHUNK, 256, 0, stream>>>(xBC, dtb, dcb, sbuf, Pbuf);
    scan_phase2_kernel<<<BATCH * NHEADS, 256, 0, stream>>>(sbuf, Pbuf);
    scan_phase3_kernel<<<BATCH * NHEADS * NCHUNK, 256, 0, stream>>>(xBC, dtb, dcb, Dp, sbuf, yraw);

    // 5) gate + RMSNorm + channel accumulation
    gate_acc_kernel<<<BATCH * 32, 256, 0, stream>>>(yraw, zx, norm_w, G);

    // 6) classifier head (G @ (W_out@W_cls) / SEQ + b_cls)
    head_kernel<<<1, 128, 0, stream>>>(G, Woc, b_cls, out);
}